// Round 3
// baseline (15137.086 us; speedup 1.0000x reference)
//
#include <hip/hip_runtime.h>
#include <stdint.h>

// ---------------------------------------------------------------------------
// 4-layer stacked LSTM -> fanout/LeakyReLU/fanin -> LSTM -> head(sigmoid)
// as one persistent producer/consumer pipeline.
//
// R3 change vs R2: REC rendezvous restructured from counter-RMW + sleep-polls
// + 3 barriers down to: data stores -> one barrier (vmcnt drain) -> relaxed
// per-part step flag; consumer waves poll flags autonomously (busy, wave-wide
// same-address loads) and pull foreign A-fragments straight into registers.
// Own K-slice MFMAs (from LDS) overlap the foreign-flag latency.
//
// k_pipe blocks (56 x 256 threads):
//   0..19  REC   (5 layers x 4 blocks) - serial recurrence, Whh in VGPRs
//   20..39 XG0-4 (4 blocks each)       - xg = h_{l-1}.Wih^T + b, 8-step chunks
//   40..47 FO    (8 blocks)            - fanout + LeakyReLU
//   48..55 FI    (8 blocks)            - fanin
// ---------------------------------------------------------------------------

#define B_ 16
#define T_ 2048
#define H_ 256
#define NG 1024
#define F_ 1024
#define CHUNK 8
#define NCH 256            // T_/CHUNK
#define WH 128             // h ring depth (steps)
#define WXG 128            // xg ring depth (steps)
#define WCH 16             // chunk-granular ring depth
#define PREC 4
#define NRECB 20
#define NBLK 56
#define APITCH 264         // LDS row pitch (bf16 elems)
#define WELEM 262144       // 1024*256
#define BND 30000000       // hot-poll safety bound

typedef __attribute__((ext_vector_type(4))) float f32x4;
typedef __attribute__((ext_vector_type(8))) short bf16x8;
typedef unsigned long long ull;

// ---- workspace layout ----
#define OFF_XG   0ul
#define SZ_XG    (5ul*WXG*NG*B_*4ul)                 // f32 [5][128][1024][16]
#define OFF_H    (OFF_XG + SZ_XG)
#define SZ_H     (5ul*WH*B_*H_*2ul)                  // bf16 [5][128][16][256]
#define OFF_FO   (OFF_H + SZ_H)
#define SZ_FO    ((unsigned long)WCH*128ul*F_*2ul)   // bf16 [16][128][1024]
#define OFF_FI   (OFF_FO + SZ_FO)
#define SZ_FI    ((unsigned long)WCH*128ul*H_*2ul)   // bf16 [16][128][256]
#define OFF_WBF  (OFF_FI + SZ_FI)
#define SZ_WBF   (7ul*WELEM*2ul)
#define OFF_H4   (OFF_WBF + SZ_WBF)
#define OFF_FLAG (OFF_H4 + 16384ul + 256ul)

// flag word indices
#define FL_STEP(l,p) (((l)*4+(p))*16)   // [20] step counters, 64B apart
#define FL_XGF(s)  (320 + (s)*16)       // [16] xg chunk flags per stage
#define FL_FOF     400                  // [16]
#define FL_FIF     416                  // [16]
#define FL_XGP(s)  (432 + (s)*4)        // [5][4] XG producer progress
#define FL_FOP     452                  // [8]
#define FL_FIP     460                  // [8]
#define FL_N       512

__device__ __forceinline__ unsigned short f2bf(float f) {
  unsigned int u = __float_as_uint(f);
  u = u + 0x7fffu + ((u >> 16) & 1u);
  return (unsigned short)(u >> 16);
}
__device__ __forceinline__ float sigm_f(float x) { return 1.0f / (1.0f + __expf(-x)); }
__device__ __forceinline__ float tanh_f(float x) {
  float e = __expf(-2.0f * fabsf(x));
  float r = (1.0f - e) / (1.0f + e);
  return x >= 0.0f ? r : -r;
}
__device__ __forceinline__ unsigned ld32(const void* p) {
  return __hip_atomic_load((const unsigned*)p, __ATOMIC_RELAXED, __HIP_MEMORY_SCOPE_AGENT);
}
__device__ __forceinline__ void st32(void* p, unsigned v) {
  __hip_atomic_store((unsigned*)p, v, __ATOMIC_RELAXED, __HIP_MEMORY_SCOPE_AGENT);
}
__device__ __forceinline__ ull ld64(const void* p) {
  return __hip_atomic_load((const ull*)p, __ATOMIC_RELAXED, __HIP_MEMORY_SCOPE_AGENT);
}
__device__ __forceinline__ void st64(void* p, ull v) {
  __hip_atomic_store((ull*)p, v, __ATOMIC_RELAXED, __HIP_MEMORY_SCOPE_AGENT);
}
// coarse spin for stream blocks (sleep ok; bounded so bugs -> wrong, not hang)
__device__ __forceinline__ void spin_ge(unsigned int* p, unsigned int tgt) {
  int n = 0;
  while (ld32(p) < tgt) {
    __builtin_amdgcn_s_sleep(1);
    if (++n > 20000000) break;
  }
}
// hot spin for REC (no sleep)
__device__ __forceinline__ void spin_hot(unsigned int* p, unsigned int tgt) {
  int n = 0;
  while (ld32(p) < tgt) { if (++n > BND) break; }
}

// ---------------------------------------------------------------------------
__global__ void k_prep(const float* __restrict__ w0ih, const float* __restrict__ w1ih,
                       const float* __restrict__ foW, const float* __restrict__ fiW,
                       unsigned char* ws) {
  unsigned short* wbf = (unsigned short*)(ws + OFF_WBF);
  unsigned int* flags = (unsigned int*)(ws + OFF_FLAG);
  if (blockIdx.x < 2) flags[blockIdx.x * 256 + threadIdx.x] = 0u;  // re-zero every launch
  int gid = blockIdx.x * 256 + threadIdx.x;
  if (gid < 7 * WELEM) {
    int which = gid >> 18;
    int idx = gid & (WELEM - 1);
    float v;
    if (which < 4)       v = w0ih[(size_t)which * WELEM + idx];
    else if (which == 4) v = w1ih[idx];
    else if (which == 5) v = foW[idx];
    else                 v = fiW[idx];
    wbf[gid] = f2bf(v);
  }
}

// ---------------------------------------------------------------------------
__global__ __launch_bounds__(256, 1) void k_pipe(
    const float* __restrict__ x,
    const float* __restrict__ w0hh, const float* __restrict__ b0,
    const float* __restrict__ fo_b, const float* __restrict__ fi_b,
    const float* __restrict__ w1hh, const float* __restrict__ b1,
    unsigned char* ws)
{
  __shared__ unsigned short smem[64 * APITCH];   // 33792 B (REC uses 2*16 rows)

  float*          xg_ring = (float*)(ws + OFF_XG);
  unsigned short* h_ring  = (unsigned short*)(ws + OFF_H);
  unsigned short* fo_ring = (unsigned short*)(ws + OFF_FO);
  unsigned short* fi_ring = (unsigned short*)(ws + OFF_FI);
  unsigned short* wbf     = (unsigned short*)(ws + OFF_WBF);
  float*          h4_last = (float*)(ws + OFF_H4);
  unsigned int*   flags   = (unsigned int*)(ws + OFF_FLAG);

  const int tid = threadIdx.x;
  const int lane = tid & 63;
  const int wave = tid >> 6;
  const int quad = lane >> 4;
  const int c16 = lane & 15;
  const int bid = blockIdx.x;

  if (bid < NRECB) {
    // ================= recurrent role: layer l, part p =================
    const int l = bid >> 2, p = bid & 3;
    const int u16 = p * 4 + wave;
    const int unit = u16 * 16 + c16;
    const float* Whh = (l < 4) ? (w0hh + (size_t)l * NG * H_) : w1hh;

    bf16x8 bfr[4][8];   // B-frags: Whh[n][k], n = gate*256+unit
#pragma unroll
    for (int g = 0; g < 4; ++g) {
      const float* rp = Whh + (size_t)(g * 256 + unit) * H_ + quad * 8;
#pragma unroll
      for (int kk = 0; kk < 8; ++kk) {
        const float* q = rp + kk * 32;
        bf16x8 pk;
#pragma unroll
        for (int jj = 0; jj < 8; ++jj) pk[jj] = (short)f2bf(q[jj]);
        bfr[g][kk] = pk;
      }
    }
    for (int i = tid; i < 2 * 16 * APITCH; i += 256) smem[i] = 0;  // h(-1)=0
    float cst[4] = {0.f, 0.f, 0.f, 0.f};
    __syncthreads();

    unsigned int* sfl = flags + FL_STEP(l, p);
    unsigned int* sf0 = flags + FL_STEP(l, (p + 1) & 3);
    unsigned int* sf1 = flags + FL_STEP(l, (p + 2) & 3);
    unsigned int* sf2 = flags + FL_STEP(l, (p + 3) & 3);
    unsigned int* xgf = flags + FL_XGF(l);

    for (int t = 0; t < T_; ++t) {
      const int cb = t & 1, nb = cb ^ 1;
      if ((t & 7) == 0) {           // per-wave chunk-boundary polls (no barrier)
        int tc = t >> 3;
        spin_hot(xgf + (tc & 15), (unsigned)(tc + 1));   // xg chunk ready
        if (l < 4 && tc >= WCH) {                        // h-ring overwrite guard
          unsigned int tgt = (unsigned)(tc - WCH + 1);
          if (l < 3) { for (int j2 = 0; j2 < 4; ++j2) spin_hot(flags + FL_XGP(l + 1) + j2, tgt); }
          else       { for (int j2 = 0; j2 < 8; ++j2) spin_hot(flags + FL_FOP + j2, tgt); }
        }
        __asm__ volatile("" ::: "memory");
      }
      // xg loads issued early (consumed post-MFMA)
      const ull* xg8 = (const ull*)(xg_ring + ((size_t)l * WXG + (size_t)(t & 127)) * (NG * B_));
      union { ull u; float f[2]; } xa[4][2];
#pragma unroll
      for (int g = 0; g < 4; ++g) {
        size_t n8 = (size_t)(g * 256 + unit) * 8 + quad * 2;
        xa[g][0].u = ld64(xg8 + n8);
        xa[g][1].u = ld64(xg8 + n8 + 1);
      }
      f32x4 ac[4];
#pragma unroll
      for (int g = 0; g < 4; ++g) ac[g] = (f32x4){0.f, 0.f, 0.f, 0.f};
      // own K-slice from LDS (overlaps foreign flag/data latency)
#pragma unroll
      for (int kq = 0; kq < 2; ++kq) {
        int kk = 2 * p + kq;
        bf16x8 af = *(const bf16x8*)(&smem[cb * 16 * APITCH + c16 * APITCH + kk * 32 + quad * 8]);
#pragma unroll
        for (int g = 0; g < 4; ++g)
          ac[g] = __builtin_amdgcn_mfma_f32_16x16x32_bf16(af, bfr[g][kk], ac[g], 0, 0, 0);
      }
      if (t > 0) {
        // wave-autonomous: poll 3 foreign step flags (same-addr wave loads)
        unsigned tgt = (unsigned)t;
        int n = 0;
        while ((ld32(sf0) < tgt) | (ld32(sf1) < tgt) | (ld32(sf2) < tgt)) {
          if (++n > BND) break;
        }
        __asm__ volatile("" ::: "memory");
        // pull foreign A-frags straight into registers (h_{t-1} ring slot)
        const unsigned short* hp =
            h_ring + ((size_t)l * WH + (size_t)((t - 1) & 127)) * (B_ * H_) + c16 * H_;
        union { ull u[2]; bf16x8 v; } faf[6];
#pragma unroll
        for (int fp = 0; fp < 3; ++fp) {
          int p2 = (p + 1 + fp) & 3;
#pragma unroll
          for (int kq = 0; kq < 2; ++kq) {
            const ull* q = (const ull*)(hp + (2 * p2 + kq) * 32 + quad * 8);
            faf[fp * 2 + kq].u[0] = ld64(q);
            faf[fp * 2 + kq].u[1] = ld64(q + 1);
          }
        }
#pragma unroll
        for (int fp = 0; fp < 3; ++fp) {
          int p2 = (p + 1 + fp) & 3;
#pragma unroll
          for (int kq = 0; kq < 2; ++kq) {
            int kk = 2 * p2 + kq;
#pragma unroll
            for (int g = 0; g < 4; ++g)
              ac[g] = __builtin_amdgcn_mfma_f32_16x16x32_bf16(faf[fp * 2 + kq].v, bfr[g][kk], ac[g], 0, 0, 0);
          }
        }
      }
      // elementwise cell; lane owns (b=quad*4+r, unit)
      unsigned short* hrw = h_ring + ((size_t)l * WH + (size_t)(t & 127)) * (B_ * H_);
      float hv[4];
#pragma unroll
      for (int r = 0; r < 4; ++r) {
        float iv = sigm_f(ac[0][r] + xa[0][r >> 1].f[r & 1]);
        float fv = sigm_f(ac[1][r] + xa[1][r >> 1].f[r & 1]);
        float gv = tanh_f(ac[2][r] + xa[2][r >> 1].f[r & 1]);
        float ov = sigm_f(ac[3][r] + xa[3][r >> 1].f[r & 1]);
        cst[r] = fv * cst[r] + iv * gv;
        hv[r] = ov * tanh_f(cst[r]);
        if (l == 4 && t == T_ - 1) h4_last[(quad * 4 + r) * H_ + unit] = hv[r];
      }
      // pack bf16 pairs via shfl; even lanes store (LDS nb buffer + ring)
#pragma unroll
      for (int r = 0; r < 4; ++r) {
        float oth = __shfl_xor(hv[r], 1, 64);
        if ((lane & 1) == 0) {
          unsigned pk = (unsigned)f2bf(hv[r]) | ((unsigned)f2bf(oth) << 16);
          int b = quad * 4 + r;
          *(unsigned*)&smem[nb * 16 * APITCH + b * APITCH + unit] = pk;
          st32(hrw + (size_t)b * H_ + unit, pk);
        }
      }
      __syncthreads();   // drains vmcnt per wave before s_barrier -> ring @ LLC
      if (tid == 0) st32(sfl, (unsigned)(t + 1));   // publish step done
    }
  } else {
    // ================= stream roles =================
    int sb = bid - NRECB, s, j, GSS;
    if (sb < 20)      { s = sb >> 2; j = sb & 3;  GSS = 4; }
    else if (sb < 28) { s = 5;       j = sb - 20; GSS = 8; }
    else              { s = 6;       j = sb - 28; GSS = 8; }
    const bool isXG = (s < 5), isFO = (s == 5), isFI = (s == 6);
    const unsigned short* Bw = wbf + (size_t)(isXG ? s : (isFO ? 5 : 6)) * WELEM;
    const float* bias = isXG ? ((s < 4) ? (b0 + s * NG) : b1) : (isFO ? fo_b : fi_b);
    unsigned int* myprog =
        flags + (isXG ? (FL_XGP(s) + j) : (isFO ? (FL_FOP + j) : (FL_FIP + j)));

    for (int tc = j; tc < NCH; tc += GSS) {
      if (tid == 0) {
        if (tc >= WCH) {  // output-ring overwrite guard
          unsigned int tgt = (unsigned)(tc - WCH + 1);
          if (isXG) {
            for (int p2 = 0; p2 < 4; ++p2) spin_ge(flags + FL_STEP(s, p2), 8u * tgt);
          } else if (isFO) {
            for (int j2 = 0; j2 < 8; ++j2) spin_ge(flags + FL_FIP + j2, tgt);
          } else {
            for (int j2 = 0; j2 < 4; ++j2) spin_ge(flags + FL_XGP(4) + j2, tgt);
          }
        }
        // input readiness
        if (isXG) {
          if (s >= 1 && s <= 3) {
            for (int p2 = 0; p2 < 4; ++p2) spin_ge(flags + FL_STEP(s - 1, p2), 8u * (unsigned)(tc + 1));
          } else if (s == 4) {
            spin_ge(flags + FL_FIF + (tc & 15), (unsigned)(tc + 1));
          }
        } else if (isFO) {
          for (int p2 = 0; p2 < 4; ++p2) spin_ge(flags + FL_STEP(3, p2), 8u * (unsigned)(tc + 1));
        } else {
          spin_ge(flags + FL_FOF + (tc & 15), (unsigned)(tc + 1));
        }
      }
      __syncthreads();

      if (!isFI) {
        // [128,256] x [256,1024]
#pragma unroll
        for (int m_blk = 0; m_blk < 2; ++m_blk) {
          __syncthreads();
          { // stage 64 A rows into LDS (bf16)
            int rloc = tid >> 2;
            int k0 = (tid & 3) * 64;
            int row = m_blk * 64 + rloc;
            int tl = row >> 4, b = row & 15;
            int t = tc * CHUNK + tl;
            unsigned short* dst = &smem[rloc * APITCH + k0];
            if (s == 0) {
              const float* src = x + ((size_t)b * T_ + t) * H_ + k0;
#pragma unroll
              for (int i = 0; i < 16; ++i) {
                f32x4 v = *(const f32x4*)(src + i * 4);
                *(unsigned*)(dst + i * 4)     = (unsigned)f2bf(v[0]) | ((unsigned)f2bf(v[1]) << 16);
                *(unsigned*)(dst + i * 4 + 2) = (unsigned)f2bf(v[2]) | ((unsigned)f2bf(v[3]) << 16);
              }
            } else {
              const unsigned short* src;
              if (isXG && s <= 3)
                src = h_ring + ((size_t)(s - 1) * WH + (size_t)(t & 127)) * (B_ * H_) + b * H_ + k0;
              else if (isXG)  // s==4: fan-in output
                src = fi_ring + ((size_t)(tc & 15) * 128 + row) * H_ + k0;
              else            // FO: h3
                src = h_ring + ((size_t)3 * WH + (size_t)(t & 127)) * (B_ * H_) + b * H_ + k0;
#pragma unroll
              for (int i = 0; i < 16; ++i)
                *(ull*)(dst + i * 4) = ld64((const ull*)src + i);
            }
          }
          __syncthreads();
          bf16x8 afr[4][8];
#pragma unroll
          for (int mt = 0; mt < 4; ++mt)
#pragma unroll
            for (int kk = 0; kk < 8; ++kk)
              afr[mt][kk] = *(const bf16x8*)(&smem[(mt * 16 + c16) * APITCH + kk * 32 + quad * 8]);
          for (int nn = 0; nn < 16; ++nn) {
            int n = (wave * 16 + nn) * 16 + c16;
            const unsigned short* bp = Bw + (size_t)n * 256 + quad * 8;
            bf16x8 bfr2[8];
#pragma unroll
            for (int kk = 0; kk < 8; ++kk) bfr2[kk] = *(const bf16x8*)(bp + kk * 32);
            f32x4 ac[4];
#pragma unroll
            for (int mt = 0; mt < 4; ++mt) ac[mt] = (f32x4){0.f, 0.f, 0.f, 0.f};
#pragma unroll
            for (int kk = 0; kk < 8; ++kk)
#pragma unroll
              for (int mt = 0; mt < 4; ++mt)
                ac[mt] = __builtin_amdgcn_mfma_f32_16x16x32_bf16(afr[mt][kk], bfr2[kk], ac[mt], 0, 0, 0);
            float bn = bias[n];
            if (isXG) {
              ull* xg8 = (ull*)(xg_ring + (size_t)s * WXG * (NG * B_));
#pragma unroll
              for (int mt = 0; mt < 4; ++mt) {
                int t = tc * CHUNK + m_blk * 4 + mt;
                size_t bi = ((size_t)(t & 127) * (NG * B_) + (size_t)n * B_ + quad * 4) >> 1;
                union { ull u; float f[2]; } u0, u1;
                u0.f[0] = ac[mt][0] + bn; u0.f[1] = ac[mt][1] + bn;
                u1.f[0] = ac[mt][2] + bn; u1.f[1] = ac[mt][3] + bn;
                st64(xg8 + bi, u0.u);
                st64(xg8 + bi + 1, u1.u);
              }
            } else {  // FO: bias + LeakyReLU -> bf16 ring
#pragma unroll
              for (int mt = 0; mt < 4; ++mt) {
                int row = m_blk * 64 + mt * 16 + quad * 4;
#pragma unroll
                for (int r = 0; r < 4; ++r) {
                  float v = ac[mt][r] + bn;
                  v = v >= 0.f ? v : 0.2f * v;
                  float oth = __shfl_xor(v, 1, 64);
                  if ((lane & 1) == 0) {
                    unsigned pk = (unsigned)f2bf(v) | ((unsigned)f2bf(oth) << 16);
                    st32(fo_ring + ((size_t)(tc & 15) * 128 + row + r) * F_ + n, pk);
                  }
                }
              }
            }
          }
        }
      } else {
        // FI: [128,1024] x [1024,256]
        f32x4 acc[2][4][4];
#pragma unroll
        for (int a1 = 0; a1 < 2; ++a1)
#pragma unroll
          for (int a2 = 0; a2 < 4; ++a2)
#pragma unroll
            for (int a3 = 0; a3 < 4; ++a3) acc[a1][a2][a3] = (f32x4){0.f, 0.f, 0.f, 0.f};
#pragma unroll
        for (int ks = 0; ks < 4; ++ks) {
#pragma unroll
          for (int m_blk = 0; m_blk < 2; ++m_blk) {
            __syncthreads();
            {
              int rloc = tid >> 2;
              int k0 = (tid & 3) * 64;
              int row = m_blk * 64 + rloc;
              const unsigned short* src =
                  fo_ring + ((size_t)(tc & 15) * 128 + row) * F_ + ks * 256 + k0;
              unsigned short* dst = &smem[rloc * APITCH + k0];
#pragma unroll
              for (int i = 0; i < 16; ++i)
                *(ull*)(dst + i * 4) = ld64((const ull*)src + i);
            }
            __syncthreads();
            bf16x8 afr[4][8];
#pragma unroll
            for (int mt = 0; mt < 4; ++mt)
#pragma unroll
              for (int kk = 0; kk < 8; ++kk)
                afr[mt][kk] = *(const bf16x8*)(&smem[(mt * 16 + c16) * APITCH + kk * 32 + quad * 8]);
#pragma unroll
            for (int nn = 0; nn < 4; ++nn) {
              int n = (wave * 4 + nn) * 16 + c16;
              const unsigned short* bp = Bw + (size_t)n * 1024 + ks * 256 + quad * 8;
              bf16x8 bfr2[8];
#pragma unroll
              for (int kk = 0; kk < 8; ++kk) bfr2[kk] = *(const bf16x8*)(bp + kk * 32);
#pragma unroll
              for (int kk = 0; kk < 8; ++kk)
#pragma unroll
                for (int mt = 0; mt < 4; ++mt)
                  acc[m_blk][nn][mt] =
                      __builtin_amdgcn_mfma_f32_16x16x32_bf16(afr[mt][kk], bfr2[kk], acc[m_blk][nn][mt], 0, 0, 0);
            }
          }
        }
#pragma unroll
        for (int m_blk = 0; m_blk < 2; ++m_blk)
#pragma unroll
          for (int nn = 0; nn < 4; ++nn) {
            int n = (wave * 4 + nn) * 16 + c16;
            float bn = bias[n];
#pragma unroll
            for (int mt = 0; mt < 4; ++mt) {
              int row = m_blk * 64 + mt * 16 + quad * 4;
#pragma unroll
              for (int r = 0; r < 4; ++r) {
                float v = acc[m_blk][nn][mt][r] + bn;
                float oth = __shfl_xor(v, 1, 64);
                if ((lane & 1) == 0) {
                  unsigned pk = (unsigned)f2bf(v) | ((unsigned)f2bf(oth) << 16);
                  st32(fi_ring + ((size_t)(tc & 15) * 128 + row + r) * H_ + n, pk);
                }
              }
            }
          }
      }
      __syncthreads();   // drains all waves' ring stores before flag publish
      if (tid == 0) {
        unsigned int* fl = isXG ? (flags + FL_XGF(s) + (tc & 15))
                                : (isFO ? (flags + FL_FOF + (tc & 15)) : (flags + FL_FIF + (tc & 15)));
        st32(fl, (unsigned)(tc + 1));
        st32(myprog, (unsigned)(tc + 1));
      }
    }
  }
}

// ---------------------------------------------------------------------------
__global__ void k_head(const float* __restrict__ hW, const float* __restrict__ hb,
                       unsigned char* ws, float* __restrict__ out) {
  __shared__ float red[256];
  const float* h4 = (const float*)(ws + OFF_H4);
  int tid = threadIdx.x;
  int b = tid >> 4, k0 = tid & 15;
  float sum = 0.f;
  for (int k = k0; k < H_; k += 16) sum += h4[b * H_ + k] * hW[k];
  red[tid] = sum;
  __syncthreads();
  if (tid < B_) {
    float z = hb[0];
    for (int i = 0; i < 16; ++i) z += red[tid * 16 + i];
    out[tid] = 1.0f / (1.0f + __expf(-z));
  }
}

// ---------------------------------------------------------------------------
extern "C" void kernel_launch(void* const* d_in, const int* in_sizes, int n_in,
                              void* d_out, int out_size, void* d_ws, size_t ws_size,
                              hipStream_t stream) {
  const float* x    = (const float*)d_in[0];
  const float* w0ih = (const float*)d_in[1];
  const float* w0hh = (const float*)d_in[2];
  const float* b0   = (const float*)d_in[3];
  const float* foW  = (const float*)d_in[4];
  const float* fob  = (const float*)d_in[5];
  const float* fiW  = (const float*)d_in[6];
  const float* fib  = (const float*)d_in[7];
  const float* w1ih = (const float*)d_in[8];
  const float* w1hh = (const float*)d_in[9];
  const float* b1   = (const float*)d_in[10];
  const float* hW   = (const float*)d_in[11];
  const float* hb   = (const float*)d_in[12];
  unsigned char* ws = (unsigned char*)d_ws;
  (void)in_sizes; (void)n_in; (void)out_size; (void)ws_size;

  hipLaunchKernelGGL(k_prep, dim3(7168), dim3(256), 0, stream, w0ih, w1ih, foW, fiW, ws);
  hipLaunchKernelGGL(k_pipe, dim3(NBLK), dim3(256), 0, stream,
                     x, w0hh, b0, fob, fib, w1hh, b1, ws);
  hipLaunchKernelGGL(k_head, dim3(1), dim3(256), 0, stream, hW, hb, ws, (float*)d_out);
}

// Round 5
// 13159.363 us; speedup vs baseline: 1.1503x; 1.1503x over previous
//
#include <hip/hip_runtime.h>
#include <stdint.h>

// ---------------------------------------------------------------------------
// 4-layer stacked LSTM -> fanout/LeakyReLU/fanin -> LSTM -> head(sigmoid).
//
// R5 = R4 architecture with the two broken stream staging loops fixed
// (XG4<-fi_ring and FI<-fo_ring staged only half their bytes with holes ->
//  uninitialized-LDS NaNs). Everything else unchanged.
//
// k_pipe blocks (41 x 512 threads):
//   0..4   REC   (1 block per layer) - Whh 48 frags/wave in VGPR + 16 in LDS,
//          per-step sync = lgkmcnt-only s_barrier, chunk-granular flags only.
//   5..24  XG0-4 (4 blocks each) : xg = h_{l-1}.Wih^T + b, 8-step chunks
//   25..32 FO    (8 blocks)      : fanout + LeakyReLU
//   33..40 FI    (8 blocks)      : fanin
// ---------------------------------------------------------------------------

#define B_ 16
#define T_ 2048
#define H_ 256
#define NG 1024
#define F_ 1024
#define CHUNK 8
#define NCH 256
#define WH 128
#define WXG 128
#define WCH 16
#define NRECB 5
#define NBLK 41
#define APITCH 264
#define WELEM 262144
#define BND 40000000
#define LDS_BYTES 147968   // 128K B-frags + 2*16*264*2 h staging

typedef __attribute__((ext_vector_type(4))) float f32x4;
typedef __attribute__((ext_vector_type(8))) short bf16x8;
typedef unsigned long long ull;

// ---- workspace layout ----
#define OFF_XG   0ul
#define SZ_XG    (5ul*WXG*NG*B_*4ul)                 // f32 [5][128][1024][16]
#define OFF_H    (OFF_XG + SZ_XG)
#define SZ_H     (5ul*WH*B_*H_*2ul)                  // bf16 [5][128][256u][16b]
#define OFF_FO   (OFF_H + SZ_H)
#define SZ_FO    ((unsigned long)WCH*128ul*F_*2ul)
#define OFF_FI   (OFF_FO + SZ_FO)
#define SZ_FI    ((unsigned long)WCH*128ul*H_*2ul)
#define OFF_WBF  (OFF_FI + SZ_FI)
#define SZ_WBF   (7ul*WELEM*2ul)
#define OFF_H4   (OFF_WBF + SZ_WBF)
#define OFF_FLAG (OFF_H4 + 16384ul + 256ul)

// flag word indices
#define FL_CHK(l)  ((l)*16)          // REC layer chunk progress (single writer)
#define FL_XGF(s)  (80 + (s)*16)     // [16] xg chunk-slot flags per stage
#define FL_FOF     160               // [16]
#define FL_FIF     176               // [16]
#define FL_XGP(s)  (192 + (s)*4)     // [5][4] XG consumer progress
#define FL_FOP     212               // [8]
#define FL_FIP     220               // [8]
#define FL_N       512

__device__ __forceinline__ unsigned short f2bf(float f) {
  unsigned int u = __float_as_uint(f);
  u = u + 0x7fffu + ((u >> 16) & 1u);
  return (unsigned short)(u >> 16);
}
__device__ __forceinline__ float sigm_f(float x) { return 1.0f / (1.0f + __expf(-x)); }
__device__ __forceinline__ float tanh_f(float x) {
  float e = __expf(-2.0f * fabsf(x));
  float r = (1.0f - e) / (1.0f + e);
  return x >= 0.0f ? r : -r;
}
__device__ __forceinline__ unsigned ld32(const void* p) {
  return __hip_atomic_load((const unsigned*)p, __ATOMIC_RELAXED, __HIP_MEMORY_SCOPE_AGENT);
}
__device__ __forceinline__ void st32(void* p, unsigned v) {
  __hip_atomic_store((unsigned*)p, v, __ATOMIC_RELAXED, __HIP_MEMORY_SCOPE_AGENT);
}
__device__ __forceinline__ ull ld64(const void* p) {
  return __hip_atomic_load((const ull*)p, __ATOMIC_RELAXED, __HIP_MEMORY_SCOPE_AGENT);
}
__device__ __forceinline__ void st64(void* p, ull v) {
  __hip_atomic_store((ull*)p, v, __ATOMIC_RELAXED, __HIP_MEMORY_SCOPE_AGENT);
}
// stream-side spin (sleep; bounded so bugs -> wrong output, not hang)
__device__ __forceinline__ void spin_ge(unsigned int* p, unsigned int tgt) {
  int n = 0;
  while (ld32(p) < tgt) {
    __builtin_amdgcn_s_sleep(1);
    if (++n > 20000000) break;
  }
}
// REC-side spin: tid0 of one block per layer only -> low LLC traffic
__device__ __forceinline__ void spin_hot(unsigned int* p, unsigned int tgt) {
  int n = 0;
  while (ld32(p) < tgt) { if (++n > BND) break; }
}

// ---------------------------------------------------------------------------
__global__ void k_prep(const float* __restrict__ w0ih, const float* __restrict__ w1ih,
                       const float* __restrict__ foW, const float* __restrict__ fiW,
                       unsigned char* ws) {
  unsigned short* wbf = (unsigned short*)(ws + OFF_WBF);
  unsigned int* flags = (unsigned int*)(ws + OFF_FLAG);
  if (blockIdx.x < 2) flags[blockIdx.x * 256 + threadIdx.x] = 0u;  // re-zero every launch
  int gid = blockIdx.x * 256 + threadIdx.x;
  if (gid < 7 * WELEM) {
    int which = gid >> 18;
    int idx = gid & (WELEM - 1);
    float v;
    if (which < 4)       v = w0ih[(size_t)which * WELEM + idx];
    else if (which == 4) v = w1ih[idx];
    else if (which == 5) v = foW[idx];
    else                 v = fiW[idx];
    wbf[gid] = f2bf(v);
  }
}

// ---------------------------------------------------------------------------
__global__ __launch_bounds__(512, 2) void k_pipe(
    const float* __restrict__ x,
    const float* __restrict__ w0hh, const float* __restrict__ b0,
    const float* __restrict__ fo_b, const float* __restrict__ fi_b,
    const float* __restrict__ w1hh, const float* __restrict__ b1,
    unsigned char* ws)
{
  extern __shared__ unsigned char dynlds[];

  float*          xg_ring = (float*)(ws + OFF_XG);
  unsigned short* h_ring  = (unsigned short*)(ws + OFF_H);
  unsigned short* fo_ring = (unsigned short*)(ws + OFF_FO);
  unsigned short* fi_ring = (unsigned short*)(ws + OFF_FI);
  unsigned short* wbf     = (unsigned short*)(ws + OFF_WBF);
  float*          h4_last = (float*)(ws + OFF_H4);
  unsigned int*   flags   = (unsigned int*)(ws + OFF_FLAG);

  const int tid  = threadIdx.x;
  const int lane = tid & 63;
  const int wave = tid >> 6;
  const int quad = lane >> 4;
  const int c16  = lane & 15;
  const int bid  = blockIdx.x;

  if (bid < NRECB) {
    // ============ recurrent role: whole layer l in this block ============
    const int l = bid;
    const float* Whh = (l < 4) ? (w0hh + (size_t)l * NG * H_) : w1hh;
    unsigned short* ldsB = (unsigned short*)dynlds;              // 128 KB
    unsigned short* hst  = (unsigned short*)(dynlds + 131072);   // 2x16xAPITCH

    // B-frags: B[k][n] = Whh[n][k]; tile j2 = gate*2 + sub, n = n0(j2)+c16.
    // kk 0..5 -> VGPR (192 regs/wave); kk 6,7 -> LDS (16 frags/wave).
    bf16x8 bfr[8][6];
#pragma unroll
    for (int j2 = 0; j2 < 8; ++j2) {
      int n = (j2 >> 1) * 256 + wave * 32 + (j2 & 1) * 16 + c16;
      const float* rp = Whh + (size_t)n * H_ + quad * 8;
#pragma unroll
      for (int kk = 0; kk < 8; ++kk) {
        bf16x8 pk;
#pragma unroll
        for (int jj = 0; jj < 8; ++jj) pk[jj] = (short)f2bf(rp[kk * 32 + jj]);
        if (kk < 6) bfr[j2][kk] = pk;
        else *(bf16x8*)(ldsB + ((wave * 8 + j2) * 2 + (kk - 6)) * 512 + lane * 8) = pk;
      }
    }
    for (int i = tid; i < 2 * 16 * APITCH; i += 512) hst[i] = 0;   // h(-1)=0
    float cst[2][4] = {{0.f,0.f,0.f,0.f},{0.f,0.f,0.f,0.f}};
    __syncthreads();

    unsigned int* chk = flags + FL_CHK(l);
    unsigned int* xgf = flags + FL_XGF(l);

    for (int t = 0; t < T_; ++t) {
      if ((t & 7) == 0) {
        int tc = t >> 3;
        __syncthreads();                       // drains vmcnt: h-ring st64s at LLC
        if (tid == 0) {
          if (tc > 0) st32(chk, (unsigned)tc); // publish chunk tc-1 complete
          spin_hot(xgf + (tc & 15), (unsigned)(tc + 1));     // xg chunk ready
          if (l < 4 && tc >= WCH) {                          // h-ring overwrite guard
            unsigned tgt = (unsigned)(tc - WCH + 1);
            if (l < 3) { for (int j2 = 0; j2 < 4; ++j2) spin_hot(flags + FL_XGP(l + 1) + j2, tgt); }
            else       { for (int j2 = 0; j2 < 8; ++j2) spin_hot(flags + FL_FOP + j2, tgt); }
          }
        }
        __syncthreads();
        __builtin_amdgcn_fence(__ATOMIC_ACQUIRE, "agent");   // inv caches: fresh xg below
      }
      const int cb = t & 1, nb = cb ^ 1;
      const float* xgs = xg_ring + ((size_t)l * WXG + (size_t)(t & 127)) * (NG * B_);
      f32x4 xgv[8];
#pragma unroll
      for (int j2 = 0; j2 < 8; ++j2) {
        int n = (j2 >> 1) * 256 + wave * 32 + (j2 & 1) * 16 + c16;
        xgv[j2] = *(const f32x4*)(xgs + (size_t)n * B_ + quad * 4);
      }
      unsigned short* hsrc = hst + cb * 16 * APITCH;
      unsigned short* hdst = hst + nb * 16 * APITCH;
      ull* hrw = (ull*)(h_ring + ((size_t)l * WH + (size_t)(t & 127)) * (B_ * H_));
#pragma unroll
      for (int s = 0; s < 2; ++s) {
        f32x4 ac[4];
#pragma unroll
        for (int g = 0; g < 4; ++g) ac[g] = xgv[g * 2 + s];   // C-init = xg
#pragma unroll
        for (int kp = 0; kp < 4; ++kp) {
          bf16x8 a0 = *(const bf16x8*)(hsrc + c16 * APITCH + (2 * kp) * 32 + quad * 8);
          bf16x8 a1 = *(const bf16x8*)(hsrc + c16 * APITCH + (2 * kp + 1) * 32 + quad * 8);
#pragma unroll
          for (int g = 0; g < 4; ++g) {
            int j2 = g * 2 + s;
            bf16x8 bb0 = (kp < 3) ? bfr[j2][2 * kp]
                : *(const bf16x8*)(ldsB + ((wave * 8 + j2) * 2 + 0) * 512 + lane * 8);
            bf16x8 bb1 = (kp < 3) ? bfr[j2][2 * kp + 1]
                : *(const bf16x8*)(ldsB + ((wave * 8 + j2) * 2 + 1) * 512 + lane * 8);
            ac[g] = __builtin_amdgcn_mfma_f32_16x16x32_bf16(a0, bb0, ac[g], 0, 0, 0);
            ac[g] = __builtin_amdgcn_mfma_f32_16x16x32_bf16(a1, bb1, ac[g], 0, 0, 0);
          }
        }
        // cell: lane owns unit u, batches quad*4+r
        int u = wave * 32 + s * 16 + c16;
        unsigned short hb[4];
#pragma unroll
        for (int r = 0; r < 4; ++r) {
          float iv = sigm_f(ac[0][r]);
          float fv = sigm_f(ac[1][r]);
          float gv = tanh_f(ac[2][r]);
          float ov = sigm_f(ac[3][r]);
          cst[s][r] = fv * cst[s][r] + iv * gv;
          float hv = ov * tanh_f(cst[s][r]);
          hb[r] = f2bf(hv);
          hdst[(quad * 4 + r) * APITCH + u] = hb[r];
          if (l == 4 && t == T_ - 1) h4_last[(quad * 4 + r) * H_ + u] = hv;
        }
        if (l < 4) {   // publish h [t][u][b]: one st64/lane, fire-and-forget
          ull pk = (ull)hb[0] | ((ull)hb[1] << 16) | ((ull)hb[2] << 32) | ((ull)hb[3] << 48);
          st64(hrw + u * 4 + quad, pk);
        }
      }
      // intra-block step barrier: LDS-only drain (vm stores stay in flight)
      asm volatile("s_waitcnt lgkmcnt(0)\n\ts_barrier" ::: "memory");
    }
    __syncthreads();
    if (tid == 0) st32(chk, (unsigned)NCH);
  } else {
    // ================= stream roles (8 waves) =================
    int sb = bid - NRECB, s, j, GSS;
    if (sb < 20)      { s = sb >> 2; j = sb & 3;  GSS = 4; }
    else if (sb < 28) { s = 5;       j = sb - 20; GSS = 8; }
    else              { s = 6;       j = sb - 28; GSS = 8; }
    const bool isXG = (s < 5), isFO = (s == 5), isFI = (s == 6);
    const unsigned short* Bw = wbf + (size_t)(isXG ? s : (isFO ? 5 : 6)) * WELEM;
    const float* bias = isXG ? ((s < 4) ? (b0 + s * NG) : b1) : (isFO ? fo_b : fi_b);
    unsigned int* myprog =
        flags + (isXG ? (FL_XGP(s) + j) : (isFO ? (FL_FOP + j) : (FL_FIP + j)));
    unsigned short* smem = (unsigned short*)dynlds;   // 64 x APITCH staging

    for (int tc = j; tc < NCH; tc += GSS) {
      if (tid == 0) {
        if (tc >= WCH) {  // output-ring overwrite guard
          unsigned tgt = (unsigned)(tc - WCH + 1);
          if (isXG)      spin_ge(flags + FL_CHK(s), tgt);
          else if (isFO) { for (int j2 = 0; j2 < 8; ++j2) spin_ge(flags + FL_FIP + j2, tgt); }
          else           { for (int j2 = 0; j2 < 4; ++j2) spin_ge(flags + FL_XGP(4) + j2, tgt); }
        }
        // input readiness
        if (isXG) {
          if (s >= 1 && s <= 3) spin_ge(flags + FL_CHK(s - 1), (unsigned)(tc + 1));
          else if (s == 4)      spin_ge(flags + FL_FIF + (tc & 15), (unsigned)(tc + 1));
        } else if (isFO) {
          spin_ge(flags + FL_CHK(3), (unsigned)(tc + 1));
        } else {
          spin_ge(flags + FL_FOF + (tc & 15), (unsigned)(tc + 1));
        }
      }
      __syncthreads();

      if (!isFI) {
#pragma unroll
        for (int m_blk = 0; m_blk < 2; ++m_blk) {
          __syncthreads();
          if ((s >= 1 && s <= 3) || isFO) {
            // h_ring [t][u][b] -> LDS rows (tl,b) x cols u  (transpose gather)
            int ls = isFO ? 3 : (s - 1);
            int tl2 = tid >> 7;              // 0..3
            int u = (tid & 127) * 2;
            int t = tc * CHUNK + m_blk * 4 + tl2;
            const ull* src = (const ull*)(h_ring + ((size_t)ls * WH + (size_t)(t & 127)) * (B_ * H_));
            ull v0[4], v1[4];
#pragma unroll
            for (int q = 0; q < 4; ++q) { v0[q] = ld64(src + u * 4 + q); v1[q] = ld64(src + (u + 1) * 4 + q); }
            int rbase = tl2 * 16;
#pragma unroll
            for (int q = 0; q < 4; ++q)
#pragma unroll
              for (int r = 0; r < 4; ++r) {
                unsigned e = (unsigned)((v0[q] >> (16 * r)) & 0xFFFFull) |
                             ((unsigned)((v1[q] >> (16 * r)) & 0xFFFFull) << 16);
                *(unsigned*)(smem + (rbase + q * 4 + r) * APITCH + u) = e;
              }
          } else if (s == 0) {
            int rloc = tid >> 3;
            int k0 = (tid & 7) * 32;
            int row = m_blk * 64 + rloc;
            int tl = row >> 4, b = row & 15;
            int t = tc * CHUNK + tl;
            const float* src = x + ((size_t)b * T_ + t) * H_ + k0;
            unsigned short* dst = smem + rloc * APITCH + k0;
#pragma unroll
            for (int i = 0; i < 8; ++i) {
              f32x4 v = *(const f32x4*)(src + i * 4);
              *(unsigned*)(dst + i * 4)     = (unsigned)f2bf(v[0]) | ((unsigned)f2bf(v[1]) << 16);
              *(unsigned*)(dst + i * 4 + 2) = (unsigned)f2bf(v[2]) | ((unsigned)f2bf(v[3]) << 16);
            }
          } else {  // s == 4: fan-in output (FIXED: contiguous 64B per thread)
            int rloc = tid >> 3;
            int k0 = (tid & 7) * 32;
            int row = m_blk * 64 + rloc;
            const unsigned short* src = fi_ring + ((size_t)(tc & 15) * 128 + row) * H_ + k0;
            unsigned short* dst = smem + rloc * APITCH + k0;
#pragma unroll
            for (int i = 0; i < 8; ++i) *(ull*)(dst + i * 4) = ld64((const ull*)src + i);
          }
          __syncthreads();
          bf16x8 afr[4][8];
#pragma unroll
          for (int mt = 0; mt < 4; ++mt)
#pragma unroll
            for (int kk = 0; kk < 8; ++kk)
              afr[mt][kk] = *(const bf16x8*)(&smem[(mt * 16 + c16) * APITCH + kk * 32 + quad * 8]);
          for (int nn = 0; nn < 8; ++nn) {
            int n = (wave * 8 + nn) * 16 + c16;
            const unsigned short* bp = Bw + (size_t)n * 256 + quad * 8;
            bf16x8 bfr2[8];
#pragma unroll
            for (int kk = 0; kk < 8; ++kk) bfr2[kk] = *(const bf16x8*)(bp + kk * 32);
            f32x4 ac[4];
#pragma unroll
            for (int mt = 0; mt < 4; ++mt) ac[mt] = (f32x4){0.f, 0.f, 0.f, 0.f};
#pragma unroll
            for (int kk = 0; kk < 8; ++kk)
#pragma unroll
              for (int mt = 0; mt < 4; ++mt)
                ac[mt] = __builtin_amdgcn_mfma_f32_16x16x32_bf16(afr[mt][kk], bfr2[kk], ac[mt], 0, 0, 0);
            float bn = bias[n];
            if (isXG) {
              ull* xg8 = (ull*)(xg_ring + (size_t)s * WXG * (NG * B_));
#pragma unroll
              for (int mt = 0; mt < 4; ++mt) {
                int t = tc * CHUNK + m_blk * 4 + mt;
                size_t bi = ((size_t)(t & 127) * (NG * B_) + (size_t)n * B_ + quad * 4) >> 1;
                union { ull u; float f[2]; } u0, u1;
                u0.f[0] = ac[mt][0] + bn; u0.f[1] = ac[mt][1] + bn;
                u1.f[0] = ac[mt][2] + bn; u1.f[1] = ac[mt][3] + bn;
                st64(xg8 + bi, u0.u);
                st64(xg8 + bi + 1, u1.u);
              }
            } else {  // FO: bias + LeakyReLU -> bf16 ring
#pragma unroll
              for (int mt = 0; mt < 4; ++mt) {
                int row = m_blk * 64 + mt * 16 + quad * 4;
#pragma unroll
                for (int r = 0; r < 4; ++r) {
                  float v = ac[mt][r] + bn;
                  v = v >= 0.f ? v : 0.2f * v;
                  float oth = __shfl_xor(v, 1, 64);
                  if ((lane & 1) == 0) {
                    unsigned pk = (unsigned)f2bf(v) | ((unsigned)f2bf(oth) << 16);
                    st32(fo_ring + ((size_t)(tc & 15) * 128 + row + r) * F_ + n, pk);
                  }
                }
              }
            }
          }
        }
      } else {
        // FI: [128,1024] x [1024,256]
        f32x4 acc[2][2][4];
#pragma unroll
        for (int a1 = 0; a1 < 2; ++a1)
#pragma unroll
          for (int a2 = 0; a2 < 2; ++a2)
#pragma unroll
            for (int a3 = 0; a3 < 4; ++a3) acc[a1][a2][a3] = (f32x4){0.f, 0.f, 0.f, 0.f};
#pragma unroll
        for (int ks = 0; ks < 4; ++ks) {
#pragma unroll
          for (int m_blk = 0; m_blk < 2; ++m_blk) {
            __syncthreads();
            {  // FIXED: contiguous 64B per thread
              int rloc = tid >> 3;
              int k0 = (tid & 7) * 32;
              int row = m_blk * 64 + rloc;
              const unsigned short* src =
                  fo_ring + ((size_t)(tc & 15) * 128 + row) * F_ + ks * 256 + k0;
              unsigned short* dst = smem + rloc * APITCH + k0;
#pragma unroll
              for (int i = 0; i < 8; ++i) *(ull*)(dst + i * 4) = ld64((const ull*)src + i);
            }
            __syncthreads();
            bf16x8 afr[4][8];
#pragma unroll
            for (int mt = 0; mt < 4; ++mt)
#pragma unroll
              for (int kk = 0; kk < 8; ++kk)
                afr[mt][kk] = *(const bf16x8*)(&smem[(mt * 16 + c16) * APITCH + kk * 32 + quad * 8]);
#pragma unroll
            for (int nn = 0; nn < 2; ++nn) {
              int n = (wave * 2 + nn) * 16 + c16;
              const unsigned short* bp = Bw + (size_t)n * 1024 + ks * 256 + quad * 8;
              bf16x8 bfr2[8];
#pragma unroll
              for (int kk = 0; kk < 8; ++kk) bfr2[kk] = *(const bf16x8*)(bp + kk * 32);
#pragma unroll
              for (int kk = 0; kk < 8; ++kk)
#pragma unroll
                for (int mt = 0; mt < 4; ++mt)
                  acc[m_blk][nn][mt] =
                      __builtin_amdgcn_mfma_f32_16x16x32_bf16(afr[mt][kk], bfr2[kk], acc[m_blk][nn][mt], 0, 0, 0);
            }
          }
        }
#pragma unroll
        for (int m_blk = 0; m_blk < 2; ++m_blk)
#pragma unroll
          for (int nn = 0; nn < 2; ++nn) {
            int n = (wave * 2 + nn) * 16 + c16;
            float bn = bias[n];
#pragma unroll
            for (int mt = 0; mt < 4; ++mt) {
              int row = m_blk * 64 + mt * 16 + quad * 4;
#pragma unroll
              for (int r = 0; r < 4; ++r) {
                float v = acc[m_blk][nn][mt][r] + bn;
                float oth = __shfl_xor(v, 1, 64);
                if ((lane & 1) == 0) {
                  unsigned pk = (unsigned)f2bf(v) | ((unsigned)f2bf(oth) << 16);
                  st32(fi_ring + ((size_t)(tc & 15) * 128 + row + r) * H_ + n, pk);
                }
              }
            }
          }
      }
      __syncthreads();   // drains ring stores before flag publish
      if (tid == 0) {
        unsigned int* fl = isXG ? (flags + FL_XGF(s) + (tc & 15))
                                : (isFO ? (flags + FL_FOF + (tc & 15)) : (flags + FL_FIF + (tc & 15)));
        st32(fl, (unsigned)(tc + 1));
        st32(myprog, (unsigned)(tc + 1));
      }
    }
  }
}

// ---------------------------------------------------------------------------
__global__ void k_head(const float* __restrict__ hW, const float* __restrict__ hb,
                       unsigned char* ws, float* __restrict__ out) {
  __shared__ float red[256];
  const float* h4 = (const float*)(ws + OFF_H4);
  int tid = threadIdx.x;
  int b = tid >> 4, k0 = tid & 15;
  float sum = 0.f;
  for (int k = k0; k < H_; k += 16) sum += h4[b * H_ + k] * hW[k];
  red[tid] = sum;
  __syncthreads();
  if (tid < B_) {
    float z = hb[0];
    for (int i = 0; i < 16; ++i) z += red[tid * 16 + i];
    out[tid] = 1.0f / (1.0f + __expf(-z));
  }
}

// ---------------------------------------------------------------------------
extern "C" void kernel_launch(void* const* d_in, const int* in_sizes, int n_in,
                              void* d_out, int out_size, void* d_ws, size_t ws_size,
                              hipStream_t stream) {
  const float* x    = (const float*)d_in[0];
  const float* w0ih = (const float*)d_in[1];
  const float* w0hh = (const float*)d_in[2];
  const float* b0   = (const float*)d_in[3];
  const float* foW  = (const float*)d_in[4];
  const float* fob  = (const float*)d_in[5];
  const float* fiW  = (const float*)d_in[6];
  const float* fib  = (const float*)d_in[7];
  const float* w1ih = (const float*)d_in[8];
  const float* w1hh = (const float*)d_in[9];
  const float* b1   = (const float*)d_in[10];
  const float* hW   = (const float*)d_in[11];
  const float* hb   = (const float*)d_in[12];
  unsigned char* ws = (unsigned char*)d_ws;
  (void)in_sizes; (void)n_in; (void)out_size; (void)ws_size;

  // host-side attribute set; idempotent, not a stream op (capture-safe)
  (void)hipFuncSetAttribute((const void*)k_pipe,
                            hipFuncAttributeMaxDynamicSharedMemorySize, LDS_BYTES);

  hipLaunchKernelGGL(k_prep, dim3(7168), dim3(256), 0, stream, w0ih, w1ih, foW, fiW, ws);
  hipLaunchKernelGGL(k_pipe, dim3(NBLK), dim3(512), LDS_BYTES, stream,
                     x, w0hh, b0, fob, fib, w1hh, b1, ws);
  hipLaunchKernelGGL(k_head, dim3(1), dim3(256), 0, stream, hW, hb, ws, (float*)d_out);
}

// Round 6
// 12201.674 us; speedup vs baseline: 1.2406x; 1.0785x over previous
//
#include <hip/hip_runtime.h>
#include <stdint.h>

// ---------------------------------------------------------------------------
// 4-layer stacked LSTM -> fanout/LeakyReLU/fanin -> LSTM -> head(sigmoid).
//
// R6 = R5 architecture (one 512-thread block per LSTM layer, Whh in
// VGPR(48 frags/wave) + LDS(16 frags/wave), lgkmcnt-only step barrier) with:
//   * xg ring in bf16 (half traffic, half registers)
//   * xg read via relaxed agent-scope atomics -> NO acquire fence, L2 stays
//     warm for weights/scratch (R5's per-chunk buffer_inv was the killer)
//   * MFMA C-init = 0; xg added in the cell -> xg LLC latency hides under
//     the MFMA chain.
//
// k_pipe blocks (41 x 512 threads):
//   0..4   REC   (1 block per layer)
//   5..24  XG0-4 (4 blocks each) : xg = h_{l-1}.Wih^T + b, 8-step chunks
//   25..32 FO    (8 blocks)      : fanout + LeakyReLU
//   33..40 FI    (8 blocks)      : fanin
// ---------------------------------------------------------------------------

#define B_ 16
#define T_ 2048
#define H_ 256
#define NG 1024
#define F_ 1024
#define CHUNK 8
#define NCH 256
#define WH 128
#define WXG 128
#define WCH 16
#define NRECB 5
#define NBLK 41
#define APITCH 264
#define WELEM 262144
#define BND 40000000
#define LDS_BYTES 147968   // 128K B-frags + 2*16*264*2 h staging

typedef __attribute__((ext_vector_type(4))) float f32x4;
typedef __attribute__((ext_vector_type(8))) short bf16x8;
typedef unsigned long long ull;

// ---- workspace layout ----
#define OFF_XG   0ul
#define SZ_XG    (5ul*WXG*NG*B_*2ul)                 // bf16 [5][128][1024][16]
#define OFF_H    (OFF_XG + SZ_XG)
#define SZ_H     (5ul*WH*B_*H_*2ul)                  // bf16 [5][128][256u][16b]
#define OFF_FO   (OFF_H + SZ_H)
#define SZ_FO    ((unsigned long)WCH*128ul*F_*2ul)
#define OFF_FI   (OFF_FO + SZ_FO)
#define SZ_FI    ((unsigned long)WCH*128ul*H_*2ul)
#define OFF_WBF  (OFF_FI + SZ_FI)
#define SZ_WBF   (7ul*WELEM*2ul)
#define OFF_H4   (OFF_WBF + SZ_WBF)
#define OFF_FLAG (OFF_H4 + 16384ul + 256ul)

// flag word indices
#define FL_CHK(l)  ((l)*16)          // REC layer chunk progress (single writer)
#define FL_XGF(s)  (80 + (s)*16)     // [16] xg chunk-slot flags per stage
#define FL_FOF     160               // [16]
#define FL_FIF     176               // [16]
#define FL_XGP(s)  (192 + (s)*4)     // [5][4] XG consumer progress
#define FL_FOP     212               // [8]
#define FL_FIP     220               // [8]
#define FL_N       512

__device__ __forceinline__ unsigned short f2bf(float f) {
  unsigned int u = __float_as_uint(f);
  u = u + 0x7fffu + ((u >> 16) & 1u);
  return (unsigned short)(u >> 16);
}
__device__ __forceinline__ float bf2f(unsigned short s) {
  return __uint_as_float((unsigned)s << 16);
}
__device__ __forceinline__ float sigm_f(float x) { return 1.0f / (1.0f + __expf(-x)); }
__device__ __forceinline__ float tanh_f(float x) {
  float e = __expf(-2.0f * fabsf(x));
  float r = (1.0f - e) / (1.0f + e);
  return x >= 0.0f ? r : -r;
}
__device__ __forceinline__ unsigned ld32(const void* p) {
  return __hip_atomic_load((const unsigned*)p, __ATOMIC_RELAXED, __HIP_MEMORY_SCOPE_AGENT);
}
__device__ __forceinline__ void st32(void* p, unsigned v) {
  __hip_atomic_store((unsigned*)p, v, __ATOMIC_RELAXED, __HIP_MEMORY_SCOPE_AGENT);
}
__device__ __forceinline__ ull ld64(const void* p) {
  return __hip_atomic_load((const ull*)p, __ATOMIC_RELAXED, __HIP_MEMORY_SCOPE_AGENT);
}
__device__ __forceinline__ void st64(void* p, ull v) {
  __hip_atomic_store((ull*)p, v, __ATOMIC_RELAXED, __HIP_MEMORY_SCOPE_AGENT);
}
// stream-side spin (sleep; bounded so bugs -> wrong output, not hang)
__device__ __forceinline__ void spin_ge(unsigned int* p, unsigned int tgt) {
  int n = 0;
  while (ld32(p) < tgt) {
    __builtin_amdgcn_s_sleep(1);
    if (++n > 20000000) break;
  }
}
// REC-side spin: tid0 of one block per layer only -> low LLC traffic
__device__ __forceinline__ void spin_hot(unsigned int* p, unsigned int tgt) {
  int n = 0;
  while (ld32(p) < tgt) { if (++n > BND) break; }
}

// ---------------------------------------------------------------------------
__global__ void k_prep(const float* __restrict__ w0ih, const float* __restrict__ w1ih,
                       const float* __restrict__ foW, const float* __restrict__ fiW,
                       unsigned char* ws) {
  unsigned short* wbf = (unsigned short*)(ws + OFF_WBF);
  unsigned int* flags = (unsigned int*)(ws + OFF_FLAG);
  if (blockIdx.x < 2) flags[blockIdx.x * 256 + threadIdx.x] = 0u;  // re-zero every launch
  int gid = blockIdx.x * 256 + threadIdx.x;
  if (gid < 7 * WELEM) {
    int which = gid >> 18;
    int idx = gid & (WELEM - 1);
    float v;
    if (which < 4)       v = w0ih[(size_t)which * WELEM + idx];
    else if (which == 4) v = w1ih[idx];
    else if (which == 5) v = foW[idx];
    else                 v = fiW[idx];
    wbf[gid] = f2bf(v);
  }
}

// ---------------------------------------------------------------------------
__global__ __launch_bounds__(512, 2) void k_pipe(
    const float* __restrict__ x,
    const float* __restrict__ w0hh, const float* __restrict__ b0,
    const float* __restrict__ fo_b, const float* __restrict__ fi_b,
    const float* __restrict__ w1hh, const float* __restrict__ b1,
    unsigned char* ws)
{
  extern __shared__ unsigned char dynlds[];

  unsigned short* xg_ring = (unsigned short*)(ws + OFF_XG);
  unsigned short* h_ring  = (unsigned short*)(ws + OFF_H);
  unsigned short* fo_ring = (unsigned short*)(ws + OFF_FO);
  unsigned short* fi_ring = (unsigned short*)(ws + OFF_FI);
  unsigned short* wbf     = (unsigned short*)(ws + OFF_WBF);
  float*          h4_last = (float*)(ws + OFF_H4);
  unsigned int*   flags   = (unsigned int*)(ws + OFF_FLAG);

  const int tid  = threadIdx.x;
  const int lane = tid & 63;
  const int wave = tid >> 6;
  const int quad = lane >> 4;
  const int c16  = lane & 15;
  const int bid  = blockIdx.x;

  if (bid < NRECB) {
    // ============ recurrent role: whole layer l in this block ============
    const int l = bid;
    const float* Whh = (l < 4) ? (w0hh + (size_t)l * NG * H_) : w1hh;
    unsigned short* ldsB = (unsigned short*)dynlds;              // 128 KB
    unsigned short* hst  = (unsigned short*)(dynlds + 131072);   // 2x16xAPITCH

    // B-frags: B[k][n] = Whh[n][k]; tile j2 = gate*2 + sub, n = n0(j2)+c16.
    // kk 0..5 -> VGPR (192 regs/wave); kk 6,7 -> LDS (16 frags/wave).
    bf16x8 bfr[8][6];
#pragma unroll
    for (int j2 = 0; j2 < 8; ++j2) {
      int n = (j2 >> 1) * 256 + wave * 32 + (j2 & 1) * 16 + c16;
      const float* rp = Whh + (size_t)n * H_ + quad * 8;
#pragma unroll
      for (int kk = 0; kk < 8; ++kk) {
        bf16x8 pk;
#pragma unroll
        for (int jj = 0; jj < 8; ++jj) pk[jj] = (short)f2bf(rp[kk * 32 + jj]);
        if (kk < 6) bfr[j2][kk] = pk;
        else *(bf16x8*)(ldsB + ((wave * 8 + j2) * 2 + (kk - 6)) * 512 + lane * 8) = pk;
      }
    }
    for (int i = tid; i < 2 * 16 * APITCH; i += 512) hst[i] = 0;   // h(-1)=0
    float cst[2][4] = {{0.f,0.f,0.f,0.f},{0.f,0.f,0.f,0.f}};
    __syncthreads();

    unsigned int* chk = flags + FL_CHK(l);
    unsigned int* xgf = flags + FL_XGF(l);

    for (int t = 0; t < T_; ++t) {
      if ((t & 7) == 0) {
        int tc = t >> 3;
        __syncthreads();                       // drains vmcnt: h-ring st64s at LLC
        if (tid == 0) {
          if (tc > 0) st32(chk, (unsigned)tc); // publish chunk tc-1 complete
          spin_hot(xgf + (tc & 15), (unsigned)(tc + 1));     // xg chunk ready
          if (l < 4 && tc >= WCH) {                          // h-ring overwrite guard
            unsigned tgt = (unsigned)(tc - WCH + 1);
            if (l < 3) { for (int j2 = 0; j2 < 4; ++j2) spin_hot(flags + FL_XGP(l + 1) + j2, tgt); }
            else       { for (int j2 = 0; j2 < 8; ++j2) spin_hot(flags + FL_FOP + j2, tgt); }
          }
        }
        __syncthreads();   // NO cache fence: xg read below via LLC-coherent atomics
      }
      const int cb = t & 1, nb = cb ^ 1;
      // xg bf16 loads (relaxed agent atomics -> LLC); consumed in cell, so
      // their latency hides under the MFMA chain.
      const ull* xg8 = (const ull*)(xg_ring + ((size_t)l * WXG + (size_t)(t & 127)) * (NG * B_));
      ull xa[8];
#pragma unroll
      for (int j2 = 0; j2 < 8; ++j2) {
        int n = (j2 >> 1) * 256 + wave * 32 + (j2 & 1) * 16 + c16;
        xa[j2] = ld64(xg8 + (size_t)n * 4 + quad);
      }
      unsigned short* hsrc = hst + cb * 16 * APITCH;
      unsigned short* hdst = hst + nb * 16 * APITCH;
      ull* hrw = (ull*)(h_ring + ((size_t)l * WH + (size_t)(t & 127)) * (B_ * H_));
#pragma unroll
      for (int s = 0; s < 2; ++s) {
        f32x4 ac[4];
#pragma unroll
        for (int g = 0; g < 4; ++g) ac[g] = (f32x4){0.f, 0.f, 0.f, 0.f};
#pragma unroll
        for (int kp = 0; kp < 4; ++kp) {
          bf16x8 a0 = *(const bf16x8*)(hsrc + c16 * APITCH + (2 * kp) * 32 + quad * 8);
          bf16x8 a1 = *(const bf16x8*)(hsrc + c16 * APITCH + (2 * kp + 1) * 32 + quad * 8);
#pragma unroll
          for (int g = 0; g < 4; ++g) {
            int j2 = g * 2 + s;
            bf16x8 bb0 = (kp < 3) ? bfr[j2][2 * kp]
                : *(const bf16x8*)(ldsB + ((wave * 8 + j2) * 2 + 0) * 512 + lane * 8);
            bf16x8 bb1 = (kp < 3) ? bfr[j2][2 * kp + 1]
                : *(const bf16x8*)(ldsB + ((wave * 8 + j2) * 2 + 1) * 512 + lane * 8);
            ac[g] = __builtin_amdgcn_mfma_f32_16x16x32_bf16(a0, bb0, ac[g], 0, 0, 0);
            ac[g] = __builtin_amdgcn_mfma_f32_16x16x32_bf16(a1, bb1, ac[g], 0, 0, 0);
          }
        }
        // cell: lane owns unit u, batches quad*4+r; xg added here (bf16->f32)
        int u = wave * 32 + s * 16 + c16;
        unsigned short hb[4];
#pragma unroll
        for (int r = 0; r < 4; ++r) {
          float xi = bf2f((unsigned short)(xa[0 * 2 + s] >> (16 * r)));
          float xf = bf2f((unsigned short)(xa[1 * 2 + s] >> (16 * r)));
          float xg = bf2f((unsigned short)(xa[2 * 2 + s] >> (16 * r)));
          float xo = bf2f((unsigned short)(xa[3 * 2 + s] >> (16 * r)));
          float iv = sigm_f(ac[0][r] + xi);
          float fv = sigm_f(ac[1][r] + xf);
          float gv = tanh_f(ac[2][r] + xg);
          float ov = sigm_f(ac[3][r] + xo);
          cst[s][r] = fv * cst[s][r] + iv * gv;
          float hv = ov * tanh_f(cst[s][r]);
          hb[r] = f2bf(hv);
          hdst[(quad * 4 + r) * APITCH + u] = hb[r];
          if (l == 4 && t == T_ - 1) h4_last[(quad * 4 + r) * H_ + u] = hv;
        }
        if (l < 4) {   // publish h [t][u][b]: one st64/lane, fire-and-forget
          ull pk = (ull)hb[0] | ((ull)hb[1] << 16) | ((ull)hb[2] << 32) | ((ull)hb[3] << 48);
          st64(hrw + u * 4 + quad, pk);
        }
      }
      // intra-block step barrier: LDS-only drain (vm stores stay in flight)
      asm volatile("s_waitcnt lgkmcnt(0)\n\ts_barrier" ::: "memory");
    }
    __syncthreads();
    if (tid == 0) st32(chk, (unsigned)NCH);
  } else {
    // ================= stream roles (8 waves) =================
    int sb = bid - NRECB, s, j, GSS;
    if (sb < 20)      { s = sb >> 2; j = sb & 3;  GSS = 4; }
    else if (sb < 28) { s = 5;       j = sb - 20; GSS = 8; }
    else              { s = 6;       j = sb - 28; GSS = 8; }
    const bool isXG = (s < 5), isFO = (s == 5), isFI = (s == 6);
    const unsigned short* Bw = wbf + (size_t)(isXG ? s : (isFO ? 5 : 6)) * WELEM;
    const float* bias = isXG ? ((s < 4) ? (b0 + s * NG) : b1) : (isFO ? fo_b : fi_b);
    unsigned int* myprog =
        flags + (isXG ? (FL_XGP(s) + j) : (isFO ? (FL_FOP + j) : (FL_FIP + j)));
    unsigned short* smem = (unsigned short*)dynlds;   // 64 x APITCH staging

    for (int tc = j; tc < NCH; tc += GSS) {
      if (tid == 0) {
        if (tc >= WCH) {  // output-ring overwrite guard
          unsigned tgt = (unsigned)(tc - WCH + 1);
          if (isXG)      spin_ge(flags + FL_CHK(s), tgt);
          else if (isFO) { for (int j2 = 0; j2 < 8; ++j2) spin_ge(flags + FL_FIP + j2, tgt); }
          else           { for (int j2 = 0; j2 < 4; ++j2) spin_ge(flags + FL_XGP(4) + j2, tgt); }
        }
        // input readiness
        if (isXG) {
          if (s >= 1 && s <= 3) spin_ge(flags + FL_CHK(s - 1), (unsigned)(tc + 1));
          else if (s == 4)      spin_ge(flags + FL_FIF + (tc & 15), (unsigned)(tc + 1));
        } else if (isFO) {
          spin_ge(flags + FL_CHK(3), (unsigned)(tc + 1));
        } else {
          spin_ge(flags + FL_FOF + (tc & 15), (unsigned)(tc + 1));
        }
      }
      __syncthreads();

      if (!isFI) {
#pragma unroll
        for (int m_blk = 0; m_blk < 2; ++m_blk) {
          __syncthreads();
          if ((s >= 1 && s <= 3) || isFO) {
            // h_ring [t][u][b] -> LDS rows (tl,b) x cols u  (transpose gather)
            int ls = isFO ? 3 : (s - 1);
            int tl2 = tid >> 7;              // 0..3
            int u = (tid & 127) * 2;
            int t = tc * CHUNK + m_blk * 4 + tl2;
            const ull* src = (const ull*)(h_ring + ((size_t)ls * WH + (size_t)(t & 127)) * (B_ * H_));
            ull v0[4], v1[4];
#pragma unroll
            for (int q = 0; q < 4; ++q) { v0[q] = ld64(src + u * 4 + q); v1[q] = ld64(src + (u + 1) * 4 + q); }
            int rbase = tl2 * 16;
#pragma unroll
            for (int q = 0; q < 4; ++q)
#pragma unroll
              for (int r = 0; r < 4; ++r) {
                unsigned e = (unsigned)((v0[q] >> (16 * r)) & 0xFFFFull) |
                             ((unsigned)((v1[q] >> (16 * r)) & 0xFFFFull) << 16);
                *(unsigned*)(smem + (rbase + q * 4 + r) * APITCH + u) = e;
              }
          } else if (s == 0) {
            int rloc = tid >> 3;
            int k0 = (tid & 7) * 32;
            int row = m_blk * 64 + rloc;
            int tl = row >> 4, b = row & 15;
            int t = tc * CHUNK + tl;
            const float* src = x + ((size_t)b * T_ + t) * H_ + k0;
            unsigned short* dst = smem + rloc * APITCH + k0;
#pragma unroll
            for (int i = 0; i < 8; ++i) {
              f32x4 v = *(const f32x4*)(src + i * 4);
              *(unsigned*)(dst + i * 4)     = (unsigned)f2bf(v[0]) | ((unsigned)f2bf(v[1]) << 16);
              *(unsigned*)(dst + i * 4 + 2) = (unsigned)f2bf(v[2]) | ((unsigned)f2bf(v[3]) << 16);
            }
          } else {  // s == 4: fan-in output (contiguous 64B per thread)
            int rloc = tid >> 3;
            int k0 = (tid & 7) * 32;
            int row = m_blk * 64 + rloc;
            const unsigned short* src = fi_ring + ((size_t)(tc & 15) * 128 + row) * H_ + k0;
            unsigned short* dst = smem + rloc * APITCH + k0;
#pragma unroll
            for (int i = 0; i < 8; ++i) *(ull*)(dst + i * 4) = ld64((const ull*)src + i);
          }
          __syncthreads();
          bf16x8 afr[4][8];
#pragma unroll
          for (int mt = 0; mt < 4; ++mt)
#pragma unroll
            for (int kk = 0; kk < 8; ++kk)
              afr[mt][kk] = *(const bf16x8*)(&smem[(mt * 16 + c16) * APITCH + kk * 32 + quad * 8]);
          for (int nn = 0; nn < 8; ++nn) {
            int n = (wave * 8 + nn) * 16 + c16;
            const unsigned short* bp = Bw + (size_t)n * 256 + quad * 8;
            bf16x8 bfr2[8];
#pragma unroll
            for (int kk = 0; kk < 8; ++kk) bfr2[kk] = *(const bf16x8*)(bp + kk * 32);
            f32x4 ac[4];
#pragma unroll
            for (int mt = 0; mt < 4; ++mt) ac[mt] = (f32x4){0.f, 0.f, 0.f, 0.f};
#pragma unroll
            for (int kk = 0; kk < 8; ++kk)
#pragma unroll
              for (int mt = 0; mt < 4; ++mt)
                ac[mt] = __builtin_amdgcn_mfma_f32_16x16x32_bf16(afr[mt][kk], bfr2[kk], ac[mt], 0, 0, 0);
            float bn = bias[n];
            if (isXG) {
              // bf16 xg ring: pack 4 batches (quad*4..+3) -> one st64
              ull* xg8 = (ull*)(xg_ring + (size_t)s * WXG * (NG * B_));
#pragma unroll
              for (int mt = 0; mt < 4; ++mt) {
                int t = tc * CHUNK + m_blk * 4 + mt;
                ull pk = (ull)f2bf(ac[mt][0] + bn) |
                         ((ull)f2bf(ac[mt][1] + bn) << 16) |
                         ((ull)f2bf(ac[mt][2] + bn) << 32) |
                         ((ull)f2bf(ac[mt][3] + bn) << 48);
                st64(xg8 + (size_t)(t & 127) * (NG * B_ / 4) + (size_t)n * 4 + quad, pk);
              }
            } else {  // FO: bias + LeakyReLU -> bf16 ring
#pragma unroll
              for (int mt = 0; mt < 4; ++mt) {
                int row = m_blk * 64 + mt * 16 + quad * 4;
#pragma unroll
                for (int r = 0; r < 4; ++r) {
                  float v = ac[mt][r] + bn;
                  v = v >= 0.f ? v : 0.2f * v;
                  float oth = __shfl_xor(v, 1, 64);
                  if ((lane & 1) == 0) {
                    unsigned pk = (unsigned)f2bf(v) | ((unsigned)f2bf(oth) << 16);
                    st32(fo_ring + ((size_t)(tc & 15) * 128 + row + r) * F_ + n, pk);
                  }
                }
              }
            }
          }
        }
      } else {
        // FI: [128,1024] x [1024,256]
        f32x4 acc[2][2][4];
#pragma unroll
        for (int a1 = 0; a1 < 2; ++a1)
#pragma unroll
          for (int a2 = 0; a2 < 2; ++a2)
#pragma unroll
            for (int a3 = 0; a3 < 4; ++a3) acc[a1][a2][a3] = (f32x4){0.f, 0.f, 0.f, 0.f};
#pragma unroll
        for (int ks = 0; ks < 4; ++ks) {
#pragma unroll
          for (int m_blk = 0; m_blk < 2; ++m_blk) {
            __syncthreads();
            {  // contiguous 64B per thread
              int rloc = tid >> 3;
              int k0 = (tid & 7) * 32;
              int row = m_blk * 64 + rloc;
              const unsigned short* src =
                  fo_ring + ((size_t)(tc & 15) * 128 + row) * F_ + ks * 256 + k0;
              unsigned short* dst = smem + rloc * APITCH + k0;
#pragma unroll
              for (int i = 0; i < 8; ++i) *(ull*)(dst + i * 4) = ld64((const ull*)src + i);
            }
            __syncthreads();
            bf16x8 afr[4][8];
#pragma unroll
            for (int mt = 0; mt < 4; ++mt)
#pragma unroll
              for (int kk = 0; kk < 8; ++kk)
                afr[mt][kk] = *(const bf16x8*)(&smem[(mt * 16 + c16) * APITCH + kk * 32 + quad * 8]);
#pragma unroll
            for (int nn = 0; nn < 2; ++nn) {
              int n = (wave * 2 + nn) * 16 + c16;
              const unsigned short* bp = Bw + (size_t)n * 1024 + ks * 256 + quad * 8;
              bf16x8 bfr2[8];
#pragma unroll
              for (int kk = 0; kk < 8; ++kk) bfr2[kk] = *(const bf16x8*)(bp + kk * 32);
#pragma unroll
              for (int kk = 0; kk < 8; ++kk)
#pragma unroll
                for (int mt = 0; mt < 4; ++mt)
                  acc[m_blk][nn][mt] =
                      __builtin_amdgcn_mfma_f32_16x16x32_bf16(afr[mt][kk], bfr2[kk], acc[m_blk][nn][mt], 0, 0, 0);
            }
          }
        }
#pragma unroll
        for (int m_blk = 0; m_blk < 2; ++m_blk)
#pragma unroll
          for (int nn = 0; nn < 2; ++nn) {
            int n = (wave * 2 + nn) * 16 + c16;
            float bn = bias[n];
#pragma unroll
            for (int mt = 0; mt < 4; ++mt) {
              int row = m_blk * 64 + mt * 16 + quad * 4;
#pragma unroll
              for (int r = 0; r < 4; ++r) {
                float v = acc[m_blk][nn][mt][r] + bn;
                float oth = __shfl_xor(v, 1, 64);
                if ((lane & 1) == 0) {
                  unsigned pk = (unsigned)f2bf(v) | ((unsigned)f2bf(oth) << 16);
                  st32(fi_ring + ((size_t)(tc & 15) * 128 + row + r) * H_ + n, pk);
                }
              }
            }
          }
      }
      __syncthreads();   // drains ring stores before flag publish
      if (tid == 0) {
        unsigned int* fl = isXG ? (flags + FL_XGF(s) + (tc & 15))
                                : (isFO ? (flags + FL_FOF + (tc & 15)) : (flags + FL_FIF + (tc & 15)));
        st32(fl, (unsigned)(tc + 1));
        st32(myprog, (unsigned)(tc + 1));
      }
    }
  }
}

// ---------------------------------------------------------------------------
__global__ void k_head(const float* __restrict__ hW, const float* __restrict__ hb,
                       unsigned char* ws, float* __restrict__ out) {
  __shared__ float red[256];
  const float* h4 = (const float*)(ws + OFF_H4);
  int tid = threadIdx.x;
  int b = tid >> 4, k0 = tid & 15;
  float sum = 0.f;
  for (int k = k0; k < H_; k += 16) sum += h4[b * H_ + k] * hW[k];
  red[tid] = sum;
  __syncthreads();
  if (tid < B_) {
    float z = hb[0];
    for (int i = 0; i < 16; ++i) z += red[tid * 16 + i];
    out[tid] = 1.0f / (1.0f + __expf(-z));
  }
}

// ---------------------------------------------------------------------------
extern "C" void kernel_launch(void* const* d_in, const int* in_sizes, int n_in,
                              void* d_out, int out_size, void* d_ws, size_t ws_size,
                              hipStream_t stream) {
  const float* x    = (const float*)d_in[0];
  const float* w0ih = (const float*)d_in[1];
  const float* w0hh = (const float*)d_in[2];
  const float* b0   = (const float*)d_in[3];
  const float* foW  = (const float*)d_in[4];
  const float* fob  = (const float*)d_in[5];
  const float* fiW  = (const float*)d_in[6];
  const float* fib  = (const float*)d_in[7];
  const float* w1ih = (const float*)d_in[8];
  const float* w1hh = (const float*)d_in[9];
  const float* b1   = (const float*)d_in[10];
  const float* hW   = (const float*)d_in[11];
  const float* hb   = (const float*)d_in[12];
  unsigned char* ws = (unsigned char*)d_ws;
  (void)in_sizes; (void)n_in; (void)out_size; (void)ws_size;

  // host-side attribute set; idempotent, not a stream op (capture-safe)
  (void)hipFuncSetAttribute((const void*)k_pipe,
                            hipFuncAttributeMaxDynamicSharedMemorySize, LDS_BYTES);

  hipLaunchKernelGGL(k_prep, dim3(7168), dim3(256), 0, stream, w0ih, w1ih, foW, fiW, ws);
  hipLaunchKernelGGL(k_pipe, dim3(NBLK), dim3(512), LDS_BYTES, stream,
                     x, w0hh, b0, fob, fib, w1hh, b1, ws);
  hipLaunchKernelGGL(k_head, dim3(1), dim3(256), 0, stream, hW, hb, ws, (float*)d_out);
}